// Round 11
// baseline (13898.776 us; speedup 1.0000x reference)
//
#include <hip/hip_runtime.h>

// LSTM: S=4096, I=64, H=1024, O=1, fp32.
// Persistent cooperative kernel, 128 blocks x 512 threads.
// R11: notification protocol replaces poll-flood (r6-r10 stuck at 2.0-2.1
// us/step; FETCH showed 6-9 full slot sweeps/step = contention feedback).
//   publish: waves post h to LDS pub[] (tagged); wave0 lanes 0..7 write 8
//            plain floats (agent-scope 4B atomic stores, one 32B burst),
//            s_waitcnt vmcnt(0), lane0 does ONE relaxed agent fetch_add.
//   consume: wave0 lane0 polls the single counter for s*NBLK (128 pollers
//            chip-wide); barrier; whole block reads all 1024 slots ONCE
//            (8B atomic loads; visibility: add was issued only after slot
//            stores ack'd at L3) -> stage LDS -> barrier -> compute.
// Overwrite safety (inductive): counter >= s*128 => every block published
// h_s => every block finished reading buffer (s-1)&1 == (s+1)&1 => safe to
// overwrite. No tags in slots, no fences anywhere.
// Weights: LDS-staged then named per-thread registers (r9 mechanics).

#define SEQ_LEN 4096
#define HID 1024
#define NBLK 128
#define TPB 512
#define HPB 8      // h-indices per block (one per wave)

__device__ __forceinline__ float fast_sigmoid(float x) {
    return __builtin_amdgcn_rcpf(1.0f + __builtin_amdgcn_exp2f(-1.4426950408889634f * x));
}
__device__ __forceinline__ float fast_tanh(float x) {
    return fmaf(-2.0f, __builtin_amdgcn_rcpf(1.0f + __builtin_amdgcn_exp2f(2.8853900817779268f * x)), 1.0f);
}

// ws layout (floats): [0..1023] hbuf0 (even s), [1024..2047] hbuf1 (odd s),
// [2048] counter (u32, own cache line). Zero-init: hbuf0 = h_0 = 0, counter=0.
__global__ void lstm_init_kernel(float* ws) {
    int t = threadIdx.x;
    #pragma unroll
    for (int k = 0; k < 8; ++k) ws[t + 256 * k] = 0.0f;
    if (t == 0) *((unsigned*)(ws + 2 * HID)) = 0u;
}

__global__ __launch_bounds__(TPB, 1) void lstm_persistent_kernel(
    const float* __restrict__ input,   // [4096][64]
    const float* __restrict__ W_ih,    // [4096][64]
    const float* __restrict__ W_hh,    // [4096][1024]
    const float* __restrict__ b_ih,    // [4096]
    const float* __restrict__ b_hh,    // [4096]
    const float* __restrict__ W_lin,   // [1][1024]
    const float* __restrict__ b_lin,   // [1]
    float* __restrict__ out,           // [1]
    float* __restrict__ ws)
{
    const int t   = threadIdx.x;
    const int b   = blockIdx.x;
    const int w   = t >> 6;      // wave in block (0..7)
    const int l   = t & 63;      // lane
    const int grp = l >> 4;      // gate q (i,f,g,o)
    const int sl  = l & 15;      // sub-lane within gate group
    const int j   = HPB * b + w; // owned h index
    const int row = grp * HID + j;

    float* hslot0 = ws;              // h buffer, even s
    float* hslot1 = ws + HID;        // h buffer, odd s
    unsigned* counter = (unsigned*)(ws + 2 * HID);

    __shared__ float4 wlds4[17 * TPB];       // 136 KB weight staging
    __shared__ float  hs[2][HID];            // double-buffered h (8 KB)
    __shared__ unsigned long long pub[HPB];  // tagged intra-block handoff
    __shared__ float  red[HPB];

    // ---- stage this block's 32 gate-rows into LDS ----
    {
        const float4* Whh4 = (const float4*)(W_hh + (size_t)row * HID);
        #pragma unroll
        for (int c = 0; c < 16; ++c)
            wlds4[c * TPB + t] = Whh4[sl + 16 * c];     // W_hh[row][64c+4sl..+3]
        wlds4[16 * TPB + t] = ((const float4*)(W_ih + (size_t)row * 64))[sl];
    }
    float bias[4];
    #pragma unroll
    for (int q = 0; q < 4; ++q) bias[q] = b_ih[q * HID + j] + b_hh[q * HID + j];
    if (t < HPB) pub[t] = 0ull;
    __syncthreads();   // weights staged, pub initialized

    // ---- LDS -> named registers (r9) ----
    const float4 W0  = wlds4[ 0 * TPB + t];
    const float4 W1  = wlds4[ 1 * TPB + t];
    const float4 W2  = wlds4[ 2 * TPB + t];
    const float4 W3  = wlds4[ 3 * TPB + t];
    const float4 W4  = wlds4[ 4 * TPB + t];
    const float4 W5  = wlds4[ 5 * TPB + t];
    const float4 W6  = wlds4[ 6 * TPB + t];
    const float4 W7  = wlds4[ 7 * TPB + t];
    const float4 W8  = wlds4[ 8 * TPB + t];
    const float4 W9  = wlds4[ 9 * TPB + t];
    const float4 W10 = wlds4[10 * TPB + t];
    const float4 W11 = wlds4[11 * TPB + t];
    const float4 W12 = wlds4[12 * TPB + t];
    const float4 W13 = wlds4[13 * TPB + t];
    const float4 W14 = wlds4[14 * TPB + t];
    const float4 W15 = wlds4[15 * TPB + t];
    const float4 W16 = wlds4[16 * TPB + t];   // W_ih fragment

    const float4* xin4 = (const float4*)input;
    float c_state = 0.0f;

    for (int s = 0; s < SEQ_LEN; ++s) {
        float4 x4 = xin4[s * 16 + sl];   // cacheable, off critical path

        // ---- notification wait: ONE poller lane per block ----
        if (t == 0) {
            const unsigned tgt = (unsigned)s * (unsigned)NBLK;
            while (__hip_atomic_load(counter, __ATOMIC_RELAXED,
                                     __HIP_MEMORY_SCOPE_AGENT) < tgt) {}
        }
        __syncthreads();   // barrier 1: counter observed => h_s slots visible

        // ---- single-shot slot read (8B atomic loads) + stage to LDS ----
        {
            const float* rsl = (s & 1) ? hslot1 : hslot0;
            unsigned long long hv = __hip_atomic_load(
                (unsigned long long*)rsl + t, __ATOMIC_RELAXED,
                __HIP_MEMORY_SCOPE_AGENT);
            float2 hp;
            hp.x = __uint_as_float((unsigned)(hv & 0xffffffffull));
            hp.y = __uint_as_float((unsigned)(hv >> 32));
            ((float2*)hs[s & 1])[t] = hp;
        }
        __syncthreads();   // barrier 2: full h_s staged

        // ---- 68 FMAs: weights from registers, h broadcast-read from LDS ----
        const float4* hs4 = (const float4*)hs[s & 1];
        float a0 = 0.f, a1 = 0.f, a2 = 0.f, a3 = 0.f;
        #define FMA_CHUNK(Wc, c, acc) { float4 h4_ = hs4[16 * (c) + sl];      \
            acc = fmaf((Wc).x, h4_.x, acc); acc = fmaf((Wc).y, h4_.y, acc);   \
            acc = fmaf((Wc).z, h4_.z, acc); acc = fmaf((Wc).w, h4_.w, acc); }
        FMA_CHUNK(W0,  0, a0) FMA_CHUNK(W1,  1, a1)
        FMA_CHUNK(W2,  2, a2) FMA_CHUNK(W3,  3, a3)
        FMA_CHUNK(W4,  4, a0) FMA_CHUNK(W5,  5, a1)
        FMA_CHUNK(W6,  6, a2) FMA_CHUNK(W7,  7, a3)
        FMA_CHUNK(W8,  8, a0) FMA_CHUNK(W9,  9, a1)
        FMA_CHUNK(W10, 10, a2) FMA_CHUNK(W11, 11, a3)
        FMA_CHUNK(W12, 12, a0) FMA_CHUNK(W13, 13, a1)
        FMA_CHUNK(W14, 14, a2) FMA_CHUNK(W15, 15, a3)
        #undef FMA_CHUNK
        a0 = fmaf(W16.x, x4.x, a0); a1 = fmaf(W16.y, x4.y, a1);
        a2 = fmaf(W16.z, x4.z, a2); a3 = fmaf(W16.w, x4.w, a3);
        float acc = (a0 + a1) + (a2 + a3);

        // reduce across 16 lanes of the gate group
        acc += __shfl_xor(acc, 1);
        acc += __shfl_xor(acc, 2);
        acc += __shfl_xor(acc, 4);
        acc += __shfl_xor(acc, 8);

        float gi = __shfl(acc, 0)  + bias[0];
        float gf = __shfl(acc, 16) + bias[1];
        float gg = __shfl(acc, 32) + bias[2];
        float go = __shfl(acc, 48) + bias[3];

        float ig = fast_sigmoid(gi);
        float fg = fast_sigmoid(gf);
        float cg = fast_tanh(gg);
        float og = fast_sigmoid(go);
        c_state  = fmaf(fg, c_state, ig * cg);
        float hn = og * fast_tanh(c_state);

        // ---- intra-block handoff: wave w lane 0 posts tagged hn to LDS ----
        const unsigned ntag = (unsigned)(s + 1);
        if (l == 0) {
            unsigned long long pv = ((unsigned long long)ntag << 32) |
                                    (unsigned long long)__float_as_uint(hn);
            __hip_atomic_store(&pub[w], pv, __ATOMIC_RELAXED, __HIP_MEMORY_SCOPE_WORKGROUP);
        }
        // ---- wave 0: gather 8 words, publish 32B burst, waitcnt, count ----
        if (w == 0) {
            if (l < HPB) {
                unsigned long long pv;
                do {
                    pv = __hip_atomic_load(&pub[l], __ATOMIC_RELAXED, __HIP_MEMORY_SCOPE_WORKGROUP);
                } while ((unsigned)(pv >> 32) != ntag);
                float* wsl = (s & 1) ? hslot0 : hslot1;   // buffer (s+1)&1
                __hip_atomic_store(&wsl[HPB * b + l],
                                   __uint_as_float((unsigned)(pv & 0xffffffffull)),
                                   __ATOMIC_RELAXED, __HIP_MEMORY_SCOPE_AGENT);
            }
            asm volatile("s_waitcnt vmcnt(0)" ::: "memory");   // slot stores ack'd at L3
            if (l == 0)
                __hip_atomic_fetch_add(counter, 1u, __ATOMIC_RELAXED,
                                       __HIP_MEMORY_SCOPE_AGENT);
        }
        // no trailing barrier: hs double-buffered; counter gates reuse
    }

    // ---- final projection: h_4096 (even -> hslot0) . W_lin + b_lin ----
    if (b == 0) {
        if (t == 0) {
            const unsigned tgt = (unsigned)SEQ_LEN * (unsigned)NBLK;
            while (__hip_atomic_load(counter, __ATOMIC_RELAXED,
                                     __HIP_MEMORY_SCOPE_AGENT) < tgt) {}
        }
        __syncthreads();
        unsigned long long hv = __hip_atomic_load(
            (unsigned long long*)hslot0 + t, __ATOMIC_RELAXED,
            __HIP_MEMORY_SCOPE_AGENT);
        float p = __uint_as_float((unsigned)(hv & 0xffffffffull)) * W_lin[2 * t] +
                  __uint_as_float((unsigned)(hv >> 32))          * W_lin[2 * t + 1];
        #pragma unroll
        for (int m = 32; m >= 1; m >>= 1) p += __shfl_xor(p, m);
        if (l == 0) red[w] = p;
        __syncthreads();
        if (t == 0) {
            float r = 0.f;
            #pragma unroll
            for (int k = 0; k < HPB; ++k) r += red[k];
            out[0] = r + b_lin[0];
        }
    }
}

extern "C" void kernel_launch(void* const* d_in, const int* in_sizes, int n_in,
                              void* d_out, int out_size, void* d_ws, size_t ws_size,
                              hipStream_t stream) {
    const float* input = (const float*)d_in[0];
    const float* W_ih  = (const float*)d_in[1];
    const float* W_hh  = (const float*)d_in[2];
    const float* b_ih  = (const float*)d_in[3];
    const float* b_hh  = (const float*)d_in[4];
    const float* W_lin = (const float*)d_in[5];
    const float* b_lin = (const float*)d_in[6];
    float* out = (float*)d_out;
    float* ws  = (float*)d_ws;

    hipLaunchKernelGGL(lstm_init_kernel, dim3(1), dim3(256), 0, stream, ws);

    void* args[] = { (void*)&input, (void*)&W_ih, (void*)&W_hh, (void*)&b_ih,
                     (void*)&b_hh, (void*)&W_lin, (void*)&b_lin, (void*)&out, (void*)&ws };
    (void)hipLaunchCooperativeKernel((void*)lstm_persistent_kernel, dim3(NBLK), dim3(TPB),
                                     args, 0, stream);
}

// Round 12
// 8711.803 us; speedup vs baseline: 1.5954x; 1.5954x over previous
//
#include <hip/hip_runtime.h>

// LSTM: S=4096, I=64, H=1024, O=1, fp32.
// Persistent cooperative kernel, 128 blocks x 512 threads (r9 champion base).
// R12 changes (publish-tail surgery):
//  1) last-wave-publishes: each wave lane0 posts tagged h to LDS pub[w] then
//     LDS fetch_add; the wave seeing old==8*(s+1)-1 is last -> pub[] complete
//     -> reads 8 words with ZERO spin and publishes the 64B line itself.
//     (deletes the wave0 wake+LDS-spin hop from every block's publish tail;
//      r8 showed a dedicated spinner doesn't help — remove the spinner.)
//  2) publish via atomic_exchange (far-atomic RMW, executes at coherence
//     point immediately, never store-buffered) instead of atomic store.
// Everything else r9: tagged slots {tag:32|h_bits:32}, relaxed agent
// atomics, tagged double buffer, zero fences, ONE __syncthreads per step,
// weights in named per-thread registers. r11 lesson: counter-notification
// serializes (128 RMWs one line + 2-phase barrier) — tagged poll overlaps
// producer skew and stays.

#define SEQ_LEN 4096
#define HID 1024
#define NBLK 128
#define TPB 512
#define HPB 8      // h-indices per block (one per wave)

__device__ __forceinline__ float fast_sigmoid(float x) {
    return __builtin_amdgcn_rcpf(1.0f + __builtin_amdgcn_exp2f(-1.4426950408889634f * x));
}
__device__ __forceinline__ float fast_tanh(float x) {
    return fmaf(-2.0f, __builtin_amdgcn_rcpf(1.0f + __builtin_amdgcn_exp2f(2.8853900817779268f * x)), 1.0f);
}

// ws: unsigned long long slots[2][1024]. {tag<<32 | fp32 bits}. Zero-init:
// buffer0 tag0/val0 == h_0 = 0 (correct); buffer1 receives odd tags.
__global__ void lstm_init_kernel(unsigned long long* ws) {
    int t = threadIdx.x;
    #pragma unroll
    for (int k = 0; k < 8; ++k) ws[t + 256 * k] = 0ull;
}

__global__ __launch_bounds__(TPB, 1) void lstm_persistent_kernel(
    const float* __restrict__ input,   // [4096][64]
    const float* __restrict__ W_ih,    // [4096][64]
    const float* __restrict__ W_hh,    // [4096][1024]
    const float* __restrict__ b_ih,    // [4096]
    const float* __restrict__ b_hh,    // [4096]
    const float* __restrict__ W_lin,   // [1][1024]
    const float* __restrict__ b_lin,   // [1]
    float* __restrict__ out,           // [1]
    unsigned long long* __restrict__ ws)
{
    const int t   = threadIdx.x;
    const int b   = blockIdx.x;
    const int w   = t >> 6;      // wave in block (0..7)
    const int l   = t & 63;      // lane
    const int grp = l >> 4;      // gate q (i,f,g,o)
    const int sl  = l & 15;      // sub-lane within gate group
    const int j   = HPB * b + w; // owned h index
    const int row = grp * HID + j;

    unsigned long long* slot0 = ws;          // even tags
    unsigned long long* slot1 = ws + HID;    // odd tags

    __shared__ float4 wlds4[17 * TPB];       // 136 KB weight staging
    __shared__ float  hs[2][HID];            // double-buffered h (8 KB)
    __shared__ unsigned long long pub[HPB];  // tagged intra-block handoff
    __shared__ unsigned pcnt;                // monotonic publish counter (LDS)
    __shared__ float  red[HPB];

    // ---- stage this block's 32 gate-rows into LDS ----
    {
        const float4* Whh4 = (const float4*)(W_hh + (size_t)row * HID);
        #pragma unroll
        for (int c = 0; c < 16; ++c)
            wlds4[c * TPB + t] = Whh4[sl + 16 * c];     // W_hh[row][64c+4sl..+3]
        wlds4[16 * TPB + t] = ((const float4*)(W_ih + (size_t)row * 64))[sl];
    }
    float bias[4];
    #pragma unroll
    for (int q = 0; q < 4; ++q) bias[q] = b_ih[q * HID + j] + b_hh[q * HID + j];
    if (t == 0) pcnt = 0u;
    if (t < HPB) pub[t] = 0ull;
    __syncthreads();   // weights staged, pub/pcnt initialized

    // ---- LDS -> named registers (r9) ----
    const float4 W0  = wlds4[ 0 * TPB + t];
    const float4 W1  = wlds4[ 1 * TPB + t];
    const float4 W2  = wlds4[ 2 * TPB + t];
    const float4 W3  = wlds4[ 3 * TPB + t];
    const float4 W4  = wlds4[ 4 * TPB + t];
    const float4 W5  = wlds4[ 5 * TPB + t];
    const float4 W6  = wlds4[ 6 * TPB + t];
    const float4 W7  = wlds4[ 7 * TPB + t];
    const float4 W8  = wlds4[ 8 * TPB + t];
    const float4 W9  = wlds4[ 9 * TPB + t];
    const float4 W10 = wlds4[10 * TPB + t];
    const float4 W11 = wlds4[11 * TPB + t];
    const float4 W12 = wlds4[12 * TPB + t];
    const float4 W13 = wlds4[13 * TPB + t];
    const float4 W14 = wlds4[14 * TPB + t];
    const float4 W15 = wlds4[15 * TPB + t];
    const float4 W16 = wlds4[16 * TPB + t];   // W_ih fragment

    const float4* xin4 = (const float4*)input;
    float c_state = 0.0f;

    for (int s = 0; s < SEQ_LEN; ++s) {
        float4 x4 = xin4[s * 16 + sl];   // issue before poll (cacheable)

        // ---- poll 2 tagged slots (relaxed agent atomics, rd-flags) ----
        unsigned long long* rs = (s & 1) ? slot1 : slot0;
        const unsigned tag = (unsigned)s;
        unsigned long long v0, v1;
        bool r0 = false, r1 = false;
        do {
            if (!r0) { v0 = __hip_atomic_load(&rs[t      ], __ATOMIC_RELAXED, __HIP_MEMORY_SCOPE_AGENT);
                       r0 = ((unsigned)(v0 >> 32) == tag); }
            if (!r1) { v1 = __hip_atomic_load(&rs[t + 512], __ATOMIC_RELAXED, __HIP_MEMORY_SCOPE_AGENT);
                       r1 = ((unsigned)(v1 >> 32) == tag); }
        } while (!(r0 && r1));

        float* hsb = hs[s & 1];
        hsb[t      ] = __uint_as_float((unsigned)(v0 & 0xffffffffull));
        hsb[t + 512] = __uint_as_float((unsigned)(v1 & 0xffffffffull));

        __syncthreads();   // the ONE barrier per step: full h_s staged

        // ---- 68 FMAs: weights from registers, h broadcast-read from LDS ----
        const float4* hs4 = (const float4*)hsb;
        float a0 = 0.f, a1 = 0.f, a2 = 0.f, a3 = 0.f;
        #define FMA_CHUNK(Wc, c, acc) { float4 h4_ = hs4[16 * (c) + sl];      \
            acc = fmaf((Wc).x, h4_.x, acc); acc = fmaf((Wc).y, h4_.y, acc);   \
            acc = fmaf((Wc).z, h4_.z, acc); acc = fmaf((Wc).w, h4_.w, acc); }
        FMA_CHUNK(W0,  0, a0) FMA_CHUNK(W1,  1, a1)
        FMA_CHUNK(W2,  2, a2) FMA_CHUNK(W3,  3, a3)
        FMA_CHUNK(W4,  4, a0) FMA_CHUNK(W5,  5, a1)
        FMA_CHUNK(W6,  6, a2) FMA_CHUNK(W7,  7, a3)
        FMA_CHUNK(W8,  8, a0) FMA_CHUNK(W9,  9, a1)
        FMA_CHUNK(W10, 10, a2) FMA_CHUNK(W11, 11, a3)
        FMA_CHUNK(W12, 12, a0) FMA_CHUNK(W13, 13, a1)
        FMA_CHUNK(W14, 14, a2) FMA_CHUNK(W15, 15, a3)
        #undef FMA_CHUNK
        a0 = fmaf(W16.x, x4.x, a0); a1 = fmaf(W16.y, x4.y, a1);
        a2 = fmaf(W16.z, x4.z, a2); a3 = fmaf(W16.w, x4.w, a3);
        float acc = (a0 + a1) + (a2 + a3);

        // reduce across 16 lanes of the gate group
        acc += __shfl_xor(acc, 1);
        acc += __shfl_xor(acc, 2);
        acc += __shfl_xor(acc, 4);
        acc += __shfl_xor(acc, 8);

        float gi = __shfl(acc, 0)  + bias[0];
        float gf = __shfl(acc, 16) + bias[1];
        float gg = __shfl(acc, 32) + bias[2];
        float go = __shfl(acc, 48) + bias[3];

        float ig = fast_sigmoid(gi);
        float fg = fast_sigmoid(gf);
        float cg = fast_tanh(gg);
        float og = fast_sigmoid(go);
        c_state  = fmaf(fg, c_state, ig * cg);
        float hn = og * fast_tanh(c_state);

        // ---- last-wave-publishes: post pub, count, last wave emits line ----
        const unsigned ntag = (unsigned)(s + 1);
        int lastw = 0;
        if (l == 0) {
            unsigned long long pv = ((unsigned long long)ntag << 32) |
                                    (unsigned long long)__float_as_uint(hn);
            __hip_atomic_store(&pub[w], pv, __ATOMIC_RELEASE, __HIP_MEMORY_SCOPE_WORKGROUP);
            unsigned old = __hip_atomic_fetch_add(&pcnt, 1u, __ATOMIC_ACQ_REL,
                                                  __HIP_MEMORY_SCOPE_WORKGROUP);
            lastw = (old == 8u * ntag - 1u) ? 1 : 0;
        }
        lastw = __shfl(lastw, 0);   // broadcast decision to the wave
        if (lastw && l < HPB) {
            // pub[] is complete (our add was the 8th) — zero-spin read
            unsigned long long pv = __hip_atomic_load(&pub[l], __ATOMIC_RELAXED,
                                                      __HIP_MEMORY_SCOPE_WORKGROUP);
            unsigned long long* wsl = (s & 1) ? slot0 : slot1;   // buffer (s+1)&1
            // far-atomic RMW: executes at coherence point, no store buffering
            (void)__hip_atomic_exchange(&wsl[HPB * b + l], pv, __ATOMIC_RELAXED,
                                        __HIP_MEMORY_SCOPE_AGENT);
        }
        // no trailing barrier: hs double-buffered; slot-tag deps bound skew
    }

    // ---- final projection: h_4096 (tag 4096, even -> slot0) . W_lin + b_lin ----
    if (b == 0) {
        const unsigned tag = (unsigned)SEQ_LEN;
        unsigned long long v0, v1;
        bool r0 = false, r1 = false;
        do {
            if (!r0) { v0 = __hip_atomic_load(&slot0[t      ], __ATOMIC_RELAXED, __HIP_MEMORY_SCOPE_AGENT);
                       r0 = ((unsigned)(v0 >> 32) == tag); }
            if (!r1) { v1 = __hip_atomic_load(&slot0[t + 512], __ATOMIC_RELAXED, __HIP_MEMORY_SCOPE_AGENT);
                       r1 = ((unsigned)(v1 >> 32) == tag); }
        } while (!(r0 && r1));
        float p = __uint_as_float((unsigned)(v0 & 0xffffffffull)) * W_lin[t] +
                  __uint_as_float((unsigned)(v1 & 0xffffffffull)) * W_lin[t + 512];
        #pragma unroll
        for (int m = 32; m >= 1; m >>= 1) p += __shfl_xor(p, m);
        if (l == 0) red[w] = p;
        __syncthreads();
        if (t == 0) {
            float r = 0.f;
            #pragma unroll
            for (int k = 0; k < HPB; ++k) r += red[k];
            out[0] = r + b_lin[0];
        }
    }
}

extern "C" void kernel_launch(void* const* d_in, const int* in_sizes, int n_in,
                              void* d_out, int out_size, void* d_ws, size_t ws_size,
                              hipStream_t stream) {
    const float* input = (const float*)d_in[0];
    const float* W_ih  = (const float*)d_in[1];
    const float* W_hh  = (const float*)d_in[2];
    const float* b_ih  = (const float*)d_in[3];
    const float* b_hh  = (const float*)d_in[4];
    const float* W_lin = (const float*)d_in[5];
    const float* b_lin = (const float*)d_in[6];
    float* out = (float*)d_out;
    unsigned long long* ws = (unsigned long long*)d_ws;

    hipLaunchKernelGGL(lstm_init_kernel, dim3(1), dim3(256), 0, stream, ws);

    void* args[] = { (void*)&input, (void*)&W_ih, (void*)&W_hh, (void*)&b_ih,
                     (void*)&b_hh, (void*)&W_lin, (void*)&b_lin, (void*)&out, (void*)&ws };
    (void)hipLaunchCooperativeKernel((void*)lstm_persistent_kernel, dim3(NBLK), dim3(TPB),
                                     args, 0, stream);
}